// Round 1
// baseline (431.506 us; speedup 1.0000x reference)
//
#include <hip/hip_runtime.h>
#include <hip/hip_bf16.h>

#define BB  4
#define HH  128
#define WW  128
#define CC  192
#define NHH 6
#define KDD 32
#define NTOT (BB*HH*WW*CC)   // 12582912
#define SCALING 0.17677669529663687f

typedef __hip_bfloat16 bf16;
typedef short bf16x8 __attribute__((ext_vector_type(8)));
typedef unsigned short ushortx4 __attribute__((ext_vector_type(4)));
typedef float floatx4 __attribute__((ext_vector_type(4)));

__device__ __forceinline__ float b2f(bf16 v) { return __bfloat162float(v); }
__device__ __forceinline__ bf16  f2b(float v) { return __float2bfloat16(v); }
__device__ __forceinline__ unsigned short f2bs(float f) {
  union { bf16 b; unsigned short u; } c; c.b = __float2bfloat16(f); return c.u;
}
__device__ __forceinline__ float s2f(short s) {
  union { unsigned u; float f; } c;
  c.u = ((unsigned)(unsigned short)s) << 16; return c.f;
}

// ---------------- K0: weight prep — transpose fp32 W -> bf16 Wt[n][k] -------
// Wt order: Wq | Wk(*SCALING) | Wv | Wo, each 192x192.
__global__ __launch_bounds__(256) void prep_kernel(
    const float* __restrict__ Wq, const float* __restrict__ Wk,
    const float* __restrict__ Wv, const float* __restrict__ Wo,
    unsigned short* __restrict__ Wt) {
  const int idx = blockIdx.x * 256 + threadIdx.x;   // 4*36864 total
  if (idx >= 4 * CC * CC) return;
  const int mat = idx / (CC * CC);
  const int rem = idx % (CC * CC);
  const int kk = rem / CC;
  const int nn = rem % CC;
  const float* W = (mat == 0) ? Wq : (mat == 1) ? Wk : (mat == 2) ? Wv : Wo;
  float val = W[kk * CC + nn];
  if (mat == 1) val *= SCALING;
  Wt[mat * CC * CC + nn * CC + kk] = f2bs(val);
}

// ---------------- K1: QKV projection via MFMA (q,k,v all bf16) --------------
// Operand-swapped MFMA: acc = mfma(Wfrag, xfrag) so each lane's 4 acc values
// are 4 CONSECUTIVE output columns of one row -> single 8B bf16x4 store.
// Grid split by matrix (3x1024 blocks) to saturate occupancy.
__global__ __launch_bounds__(256) void qkv_mfma(
    const float* __restrict__ x, const unsigned short* __restrict__ Wt,
    const float* __restrict__ bq, const float* __restrict__ bk,
    const float* __restrict__ bv,
    bf16* __restrict__ q, bf16* __restrict__ k, bf16* __restrict__ v) {
  const int wave = threadIdx.x >> 6, l = threadIdx.x & 63;
  const int r16 = l & 15, quad = l >> 4;
  const int mat = blockIdx.x >> 10;                 // 0..2
  const int row0 = (blockIdx.x & 1023) * 64 + wave * 16;
  const floatx4 zero = {0.f, 0.f, 0.f, 0.f};
  bf16x8 a[6];
  const float* xrow = x + (row0 + r16) * CC;
  #pragma unroll
  for (int kc = 0; kc < 6; ++kc) {
    const float4* p = reinterpret_cast<const float4*>(xrow + kc * 32 + quad * 8);
    float4 u0 = p[0], u1 = p[1];
    bf16x8 t;
    t[0]=f2bs(u0.x); t[1]=f2bs(u0.y); t[2]=f2bs(u0.z); t[3]=f2bs(u0.w);
    t[4]=f2bs(u1.x); t[5]=f2bs(u1.y); t[6]=f2bs(u1.z); t[7]=f2bs(u1.w);
    a[kc] = t;
  }
  const unsigned short* Wm = Wt + mat * CC * CC;
  bf16* outp = (mat == 0) ? q : (mat == 1) ? k : v;
  const float* bias = (mat == 0) ? bq : (mat == 1) ? bk : bv;
  const float bscale = (mat == 1) ? SCALING : 1.f;
  #pragma unroll
  for (int nt = 0; nt < 12; ++nt) {
    floatx4 acc = zero;
    #pragma unroll
    for (int kc = 0; kc < 6; ++kc) {
      bf16x8 bfr = *reinterpret_cast<const bf16x8*>(
          Wm + (nt * 16 + r16) * CC + kc * 32 + quad * 8);
      // swapped operands: D row-dim = W's n index, D col-dim = x's row index
      acc = __builtin_amdgcn_mfma_f32_16x16x32_bf16(bfr, a[kc], acc, 0, 0, 0);
    }
    const int col0 = nt * 16 + quad * 4;
    const float4 b4 = *reinterpret_cast<const float4*>(bias + col0);
    ushortx4 st;
    st[0] = f2bs(acc[0] + b4.x * bscale);
    st[1] = f2bs(acc[1] + b4.y * bscale);
    st[2] = f2bs(acc[2] + b4.z * bscale);
    st[3] = f2bs(acc[3] + b4.w * bscale);
    *reinterpret_cast<ushortx4*>(&outp[(row0 + r16) * CC + col0]) = st;
  }
}

// ---------------- K2: depthwise 5x5 conv (LEPE), 8 channels/thread ----------
__global__ __launch_bounds__(256) void lepe_kernel(
    const bf16* __restrict__ v, const float* __restrict__ kw,
    const float* __restrict__ kb, float* __restrict__ lepe) {
  const int tid = blockIdx.x * 256 + threadIdx.x;    // NTOT/8 threads
  const int c8 = tid % (CC / 8);
  const int w  = (tid / (CC / 8)) % WW;
  const int h  = (tid / ((CC / 8) * WW)) % HH;
  const int b  = tid / ((CC / 8) * WW * HH);
  const int c0 = c8 * 8;
  float acc[8];
  {
    const float4* kbp = reinterpret_cast<const float4*>(kb + c0);
    float4 b0 = kbp[0], b1 = kbp[1];
    acc[0]=b0.x; acc[1]=b0.y; acc[2]=b0.z; acc[3]=b0.w;
    acc[4]=b1.x; acc[5]=b1.y; acc[6]=b1.z; acc[7]=b1.w;
  }
  #pragma unroll
  for (int kh = 0; kh < 5; ++kh) {
    const int hh = h + kh - 2;
    if ((unsigned)hh >= HH) continue;
    #pragma unroll
    for (int kwi = 0; kwi < 5; ++kwi) {
      const int ww = w + kwi - 2;
      if ((unsigned)ww >= WW) continue;
      bf16x8 vv = *reinterpret_cast<const bf16x8*>(
          v + ((b * HH + hh) * WW + ww) * CC + c0);
      const float4* kp = reinterpret_cast<const float4*>(
          kw + (kh * 5 + kwi) * CC + c0);
      float4 k0 = kp[0], k1 = kp[1];
      acc[0] = fmaf(s2f(vv[0]), k0.x, acc[0]);
      acc[1] = fmaf(s2f(vv[1]), k0.y, acc[1]);
      acc[2] = fmaf(s2f(vv[2]), k0.z, acc[2]);
      acc[3] = fmaf(s2f(vv[3]), k0.w, acc[3]);
      acc[4] = fmaf(s2f(vv[4]), k1.x, acc[4]);
      acc[5] = fmaf(s2f(vv[5]), k1.y, acc[5]);
      acc[6] = fmaf(s2f(vv[6]), k1.z, acc[6]);
      acc[7] = fmaf(s2f(vv[7]), k1.w, acc[7]);
    }
  }
  float4* op = reinterpret_cast<float4*>(lepe + ((b * HH + h) * WW + w) * CC + c0);
  op[0] = make_float4(acc[0], acc[1], acc[2], acc[3]);
  op[1] = make_float4(acc[4], acc[5], acc[6], acc[7]);
}

// ---------------- K3/K4: MFMA attention (row or column axis) ----------------
__global__ __launch_bounds__(64) void attn_mfma_kernel(
    const bf16* __restrict__ qg, const bf16* __restrict__ kg,
    bf16* vbuf, const float* __restrict__ mask,
    const float* __restrict__ lepeadd, const int rstride, const int is_col) {
  __shared__ unsigned short P[16 * 136];
  const int bx = blockIdx.x;
  const int n = bx % NHH;
  const int p = (bx / NHH) % 128;
  const int b = bx / (NHH * 128);
  const int base = is_col ? ((b * HH * WW + p) * CC + n * KDD)
                          : (((b * HH + p) * WW) * CC + n * KDD);
  const int l = threadIdx.x;
  const int r16 = l & 15, quad = l >> 4;
  const float* mbase = mask + n * 128 * 128;
  const floatx4 zero = {0.f, 0.f, 0.f, 0.f};
  const short* vs = (const short*)vbuf;

  bf16x8 kf[8];
  #pragma unroll
  for (int ni = 0; ni < 8; ++ni) {
    kf[ni] = *reinterpret_cast<const bf16x8*>(
        kg + base + (ni * 16 + r16) * rstride + quad * 8);
  }
  bf16x8 vf[4][2];
  #pragma unroll
  for (int s = 0; s < 4; ++s) {
    #pragma unroll
    for (int nj = 0; nj < 2; ++nj) {
      bf16x8 t;
      #pragma unroll
      for (int j = 0; j < 8; ++j) {
        const int key = s * 32 + quad * 8 + j;
        t[j] = vs[base + key * rstride + nj * 16 + r16];
      }
      vf[s][nj] = t;
    }
  }

  for (int mi = 0; mi < 8; ++mi) {
    bf16x8 qf = *reinterpret_cast<const bf16x8*>(
        qg + base + (mi * 16 + r16) * rstride + quad * 8);
    floatx4 S[8];
    #pragma unroll
    for (int ni = 0; ni < 8; ++ni)
      S[ni] = __builtin_amdgcn_mfma_f32_16x16x32_bf16(qf, kf[ni], zero, 0, 0, 0);
    #pragma unroll
    for (int ni = 0; ni < 8; ++ni)
      #pragma unroll
      for (int i = 0; i < 4; ++i)
        S[ni][i] += mbase[(mi * 16 + quad * 4 + i) * 128 + ni * 16 + r16];
    float linv[4], mrow[4];
    #pragma unroll
    for (int i = 0; i < 4; ++i) {
      float m = S[0][i];
      #pragma unroll
      for (int ni = 1; ni < 8; ++ni) m = fmaxf(m, S[ni][i]);
      m = fmaxf(m, __shfl_xor(m, 1));
      m = fmaxf(m, __shfl_xor(m, 2));
      m = fmaxf(m, __shfl_xor(m, 4));
      m = fmaxf(m, __shfl_xor(m, 8));
      mrow[i] = m;
    }
    #pragma unroll
    for (int i = 0; i < 4; ++i) {
      float lsum = 0.f;
      #pragma unroll
      for (int ni = 0; ni < 8; ++ni) {
        const float pv = __expf(S[ni][i] - mrow[i]);
        S[ni][i] = pv;
        lsum += pv;
      }
      lsum += __shfl_xor(lsum, 1);
      lsum += __shfl_xor(lsum, 2);
      lsum += __shfl_xor(lsum, 4);
      lsum += __shfl_xor(lsum, 8);
      linv[i] = 1.f / lsum;
    }
    #pragma unroll
    for (int ni = 0; ni < 8; ++ni)
      #pragma unroll
      for (int i = 0; i < 4; ++i)
        P[(quad * 4 + i) * 136 + ni * 16 + r16] = f2bs(S[ni][i] * linv[i]);
    floatx4 O[2] = {zero, zero};
    #pragma unroll
    for (int s = 0; s < 4; ++s) {
      bf16x8 pf = *reinterpret_cast<const bf16x8*>(
          &P[r16 * 136 + s * 32 + quad * 8]);
      #pragma unroll
      for (int nj = 0; nj < 2; ++nj)
        O[nj] = __builtin_amdgcn_mfma_f32_16x16x32_bf16(pf, vf[s][nj], O[nj], 0, 0, 0);
    }
    #pragma unroll
    for (int nj = 0; nj < 2; ++nj)
      #pragma unroll
      for (int i = 0; i < 4; ++i) {
        const int addr = base + (mi * 16 + quad * 4 + i) * rstride + nj * 16 + r16;
        float val = O[nj][i];
        if (lepeadd) val += lepeadd[addr];
        vbuf[addr] = f2b(val);
      }
  }
}

// ---------------- K5: output projection via MFMA (bf16 pre -> fp32 out) -----
// Operand-swapped MFMA -> each lane's 4 acc values are 4 consecutive output
// columns -> single float4 store. nt split across 2 blocks for occupancy.
__global__ __launch_bounds__(256) void proj_mfma(
    const bf16* __restrict__ pre, const unsigned short* __restrict__ Wto,
    const float* __restrict__ bo, float* __restrict__ out) {
  const int wave = threadIdx.x >> 6, l = threadIdx.x & 63;
  const int r16 = l & 15, quad = l >> 4;
  const int half = blockIdx.x & 1;                  // nt 0..5 or 6..11
  const int row0 = (blockIdx.x >> 1) * 64 + wave * 16;
  const floatx4 zero = {0.f, 0.f, 0.f, 0.f};
  bf16x8 a[6];
  #pragma unroll
  for (int kc = 0; kc < 6; ++kc)
    a[kc] = *reinterpret_cast<const bf16x8*>(
        pre + (row0 + r16) * CC + kc * 32 + quad * 8);
  #pragma unroll
  for (int t = 0; t < 6; ++t) {
    const int nt = half * 6 + t;
    floatx4 acc = zero;
    #pragma unroll
    for (int kc = 0; kc < 6; ++kc) {
      bf16x8 bfr = *reinterpret_cast<const bf16x8*>(
          Wto + (nt * 16 + r16) * CC + kc * 32 + quad * 8);
      acc = __builtin_amdgcn_mfma_f32_16x16x32_bf16(bfr, a[kc], acc, 0, 0, 0);
    }
    const int col0 = nt * 16 + quad * 4;
    const float4 b4 = *reinterpret_cast<const float4*>(bo + col0);
    float4 st = make_float4(acc[0] + b4.x, acc[1] + b4.y,
                            acc[2] + b4.z, acc[3] + b4.w);
    *reinterpret_cast<float4*>(&out[(row0 + r16) * CC + col0]) = st;
  }
}

extern "C" void kernel_launch(void* const* d_in, const int* in_sizes, int n_in,
                              void* d_out, int out_size, void* d_ws, size_t ws_size,
                              hipStream_t stream) {
  const float* x      = (const float*)d_in[0];
  const float* mask_h = (const float*)d_in[1];
  const float* mask_w = (const float*)d_in[2];
  const float* Wq = (const float*)d_in[3];
  const float* bq = (const float*)d_in[4];
  const float* Wk = (const float*)d_in[5];
  const float* bk = (const float*)d_in[6];
  const float* Wv = (const float*)d_in[7];
  const float* bv = (const float*)d_in[8];
  const float* lw = (const float*)d_in[9];
  const float* lb = (const float*)d_in[10];
  const float* Wo = (const float*)d_in[11];
  const float* bo = (const float*)d_in[12];
  float* out = (float*)d_out;

  // ws: q bf16 | k bf16 | v bf16 (each NTOT) | Wt bf16 4x192x192 = 75.8 MB
  bf16* q    = (bf16*)d_ws;
  bf16* kbuf = q + NTOT;
  bf16* v    = kbuf + NTOT;
  unsigned short* Wt = (unsigned short*)(v + NTOT);

  prep_kernel<<<(4*CC*CC + 255)/256, 256, 0, stream>>>(Wq, Wk, Wv, Wo, Wt);
  qkv_mfma<<<3 * (BB*HH*WW)/64, 256, 0, stream>>>(x, Wt, bq, bk, bv, q, kbuf, v);
  lepe_kernel<<<(NTOT/8 + 255)/256, 256, 0, stream>>>(v, lw, lb, out);  // out = lepe
  attn_mfma_kernel<<<BB*128*NHH, 64, 0, stream>>>(
      q, kbuf, v, mask_w, nullptr, CC, 0);                  // v := v1
  attn_mfma_kernel<<<BB*128*NHH, 64, 0, stream>>>(
      q, kbuf, v, mask_h, out, WW*CC, 1);                   // v := attn+lepe
  proj_mfma<<<2 * (BB*HH*WW)/64, 256, 0, stream>>>(v, Wt + 3*CC*CC, bo, out);
}

// Round 2
// 357.082 us; speedup vs baseline: 1.2084x; 1.2084x over previous
//
#include <hip/hip_runtime.h>
#include <hip/hip_bf16.h>

#define BB  4
#define HH  128
#define WW  128
#define CC  192
#define NHH 6
#define KDD 32
#define NTOT (BB*HH*WW*CC)   // 12582912
#define SCALING 0.17677669529663687f

typedef __hip_bfloat16 bf16;
typedef short bf16x8 __attribute__((ext_vector_type(8)));
typedef unsigned short ushortx4 __attribute__((ext_vector_type(4)));
typedef float floatx4 __attribute__((ext_vector_type(4)));

__device__ __forceinline__ float b2f(bf16 v) { return __bfloat162float(v); }
__device__ __forceinline__ bf16  f2b(float v) { return __float2bfloat16(v); }
__device__ __forceinline__ unsigned short f2bs(float f) {
  union { bf16 b; unsigned short u; } c; c.b = __float2bfloat16(f); return c.u;
}
__device__ __forceinline__ float s2f(short s) {
  union { unsigned u; float f; } c;
  c.u = ((unsigned)(unsigned short)s) << 16; return c.f;
}

// ---------------- K0: weight prep — transpose fp32 W -> bf16 Wt[n][k] -------
// Wt order: Wq | Wk(*SCALING) | Wv | Wo, each 192x192.
__global__ __launch_bounds__(256) void prep_kernel(
    const float* __restrict__ Wq, const float* __restrict__ Wk,
    const float* __restrict__ Wv, const float* __restrict__ Wo,
    unsigned short* __restrict__ Wt) {
  const int idx = blockIdx.x * 256 + threadIdx.x;   // 4*36864 total
  if (idx >= 4 * CC * CC) return;
  const int mat = idx / (CC * CC);
  const int rem = idx % (CC * CC);
  const int kk = rem / CC;
  const int nn = rem % CC;
  const float* W = (mat == 0) ? Wq : (mat == 1) ? Wk : (mat == 2) ? Wv : Wo;
  float val = W[kk * CC + nn];
  if (mat == 1) val *= SCALING;
  Wt[mat * CC * CC + nn * CC + kk] = f2bs(val);
}

// ---------------- K1: QKV projection via MFMA (q,k,v all bf16) --------------
// v3: 2 row-fragments per wave (32 rows) + all 3 matrices fused per block.
//  - Each W fragment load feeds 2 independent MFMAs (ILP behind s_waitcnt).
//  - W L2 traffic halves vs 16-row waves; x is fetched exactly once.
//  - Operand-swapped MFMA (W as A-operand) -> lane's 4 acc values are 4
//    consecutive output columns of one row -> single 8B bf16x4 store.
__global__ __launch_bounds__(256) void qkv_mfma(
    const float* __restrict__ x, const unsigned short* __restrict__ Wt,
    const float* __restrict__ bq, const float* __restrict__ bk,
    const float* __restrict__ bv,
    bf16* __restrict__ q, bf16* __restrict__ k, bf16* __restrict__ v) {
  const int wave = threadIdx.x >> 6, l = threadIdx.x & 63;
  const int r16 = l & 15, quad = l >> 4;
  const int row0 = blockIdx.x * 128 + wave * 32;    // wave covers 32 rows
  const floatx4 zero = {0.f, 0.f, 0.f, 0.f};
  bf16x8 a[2][6];
  #pragma unroll
  for (int rs = 0; rs < 2; ++rs) {
    const float* xrow = x + (row0 + rs * 16 + r16) * CC;
    #pragma unroll
    for (int kc = 0; kc < 6; ++kc) {
      const float4* p = reinterpret_cast<const float4*>(xrow + kc * 32 + quad * 8);
      float4 u0 = p[0], u1 = p[1];
      bf16x8 t;
      t[0]=f2bs(u0.x); t[1]=f2bs(u0.y); t[2]=f2bs(u0.z); t[3]=f2bs(u0.w);
      t[4]=f2bs(u1.x); t[5]=f2bs(u1.y); t[6]=f2bs(u1.z); t[7]=f2bs(u1.w);
      a[rs][kc] = t;
    }
  }
  #pragma unroll
  for (int mat = 0; mat < 3; ++mat) {
    const unsigned short* Wm = Wt + mat * CC * CC;
    bf16* outp = (mat == 0) ? q : (mat == 1) ? k : v;
    const float* bias = (mat == 0) ? bq : (mat == 1) ? bk : bv;
    const float bscale = (mat == 1) ? SCALING : 1.f;
    #pragma unroll
    for (int nt = 0; nt < 12; ++nt) {
      bf16x8 wfr[6];
      #pragma unroll
      for (int kc = 0; kc < 6; ++kc)
        wfr[kc] = *reinterpret_cast<const bf16x8*>(
            Wm + (nt * 16 + r16) * CC + kc * 32 + quad * 8);
      floatx4 acc0 = zero, acc1 = zero;
      #pragma unroll
      for (int kc = 0; kc < 6; ++kc) {
        acc0 = __builtin_amdgcn_mfma_f32_16x16x32_bf16(wfr[kc], a[0][kc], acc0, 0, 0, 0);
        acc1 = __builtin_amdgcn_mfma_f32_16x16x32_bf16(wfr[kc], a[1][kc], acc1, 0, 0, 0);
      }
      const int col0 = nt * 16 + quad * 4;
      const float4 b4 = *reinterpret_cast<const float4*>(bias + col0);
      ushortx4 s0, s1;
      s0[0] = f2bs(acc0[0] + b4.x * bscale);
      s0[1] = f2bs(acc0[1] + b4.y * bscale);
      s0[2] = f2bs(acc0[2] + b4.z * bscale);
      s0[3] = f2bs(acc0[3] + b4.w * bscale);
      s1[0] = f2bs(acc1[0] + b4.x * bscale);
      s1[1] = f2bs(acc1[1] + b4.y * bscale);
      s1[2] = f2bs(acc1[2] + b4.z * bscale);
      s1[3] = f2bs(acc1[3] + b4.w * bscale);
      *reinterpret_cast<ushortx4*>(&outp[(row0 + r16) * CC + col0]) = s0;
      *reinterpret_cast<ushortx4*>(&outp[(row0 + 16 + r16) * CC + col0]) = s1;
    }
  }
}

// ---------------- K2: depthwise 5x5 conv (LEPE), 8 channels/thread ----------
__global__ __launch_bounds__(256) void lepe_kernel(
    const bf16* __restrict__ v, const float* __restrict__ kw,
    const float* __restrict__ kb, float* __restrict__ lepe) {
  const int tid = blockIdx.x * 256 + threadIdx.x;    // NTOT/8 threads
  const int c8 = tid % (CC / 8);
  const int w  = (tid / (CC / 8)) % WW;
  const int h  = (tid / ((CC / 8) * WW)) % HH;
  const int b  = tid / ((CC / 8) * WW * HH);
  const int c0 = c8 * 8;
  float acc[8];
  {
    const float4* kbp = reinterpret_cast<const float4*>(kb + c0);
    float4 b0 = kbp[0], b1 = kbp[1];
    acc[0]=b0.x; acc[1]=b0.y; acc[2]=b0.z; acc[3]=b0.w;
    acc[4]=b1.x; acc[5]=b1.y; acc[6]=b1.z; acc[7]=b1.w;
  }
  #pragma unroll
  for (int kh = 0; kh < 5; ++kh) {
    const int hh = h + kh - 2;
    if ((unsigned)hh >= HH) continue;
    #pragma unroll
    for (int kwi = 0; kwi < 5; ++kwi) {
      const int ww = w + kwi - 2;
      if ((unsigned)ww >= WW) continue;
      bf16x8 vv = *reinterpret_cast<const bf16x8*>(
          v + ((b * HH + hh) * WW + ww) * CC + c0);
      const float4* kp = reinterpret_cast<const float4*>(
          kw + (kh * 5 + kwi) * CC + c0);
      float4 k0 = kp[0], k1 = kp[1];
      acc[0] = fmaf(s2f(vv[0]), k0.x, acc[0]);
      acc[1] = fmaf(s2f(vv[1]), k0.y, acc[1]);
      acc[2] = fmaf(s2f(vv[2]), k0.z, acc[2]);
      acc[3] = fmaf(s2f(vv[3]), k0.w, acc[3]);
      acc[4] = fmaf(s2f(vv[4]), k1.x, acc[4]);
      acc[5] = fmaf(s2f(vv[5]), k1.y, acc[5]);
      acc[6] = fmaf(s2f(vv[6]), k1.z, acc[6]);
      acc[7] = fmaf(s2f(vv[7]), k1.w, acc[7]);
    }
  }
  float4* op = reinterpret_cast<float4*>(lepe + ((b * HH + h) * WW + w) * CC + c0);
  op[0] = make_float4(acc[0], acc[1], acc[2], acc[3]);
  op[1] = make_float4(acc[4], acc[5], acc[6], acc[7]);
}

// ---------------- K3/K4: MFMA attention (row or column axis) ----------------
__global__ __launch_bounds__(64) void attn_mfma_kernel(
    const bf16* __restrict__ qg, const bf16* __restrict__ kg,
    bf16* vbuf, const float* __restrict__ mask,
    const float* __restrict__ lepeadd, const int rstride, const int is_col) {
  __shared__ unsigned short P[16 * 136];
  const int bx = blockIdx.x;
  const int n = bx % NHH;
  const int p = (bx / NHH) % 128;
  const int b = bx / (NHH * 128);
  const int base = is_col ? ((b * HH * WW + p) * CC + n * KDD)
                          : (((b * HH + p) * WW) * CC + n * KDD);
  const int l = threadIdx.x;
  const int r16 = l & 15, quad = l >> 4;
  const float* mbase = mask + n * 128 * 128;
  const floatx4 zero = {0.f, 0.f, 0.f, 0.f};
  const short* vs = (const short*)vbuf;

  bf16x8 kf[8];
  #pragma unroll
  for (int ni = 0; ni < 8; ++ni) {
    kf[ni] = *reinterpret_cast<const bf16x8*>(
        kg + base + (ni * 16 + r16) * rstride + quad * 8);
  }
  bf16x8 vf[4][2];
  #pragma unroll
  for (int s = 0; s < 4; ++s) {
    #pragma unroll
    for (int nj = 0; nj < 2; ++nj) {
      bf16x8 t;
      #pragma unroll
      for (int j = 0; j < 8; ++j) {
        const int key = s * 32 + quad * 8 + j;
        t[j] = vs[base + key * rstride + nj * 16 + r16];
      }
      vf[s][nj] = t;
    }
  }

  for (int mi = 0; mi < 8; ++mi) {
    bf16x8 qf = *reinterpret_cast<const bf16x8*>(
        qg + base + (mi * 16 + r16) * rstride + quad * 8);
    floatx4 S[8];
    #pragma unroll
    for (int ni = 0; ni < 8; ++ni)
      S[ni] = __builtin_amdgcn_mfma_f32_16x16x32_bf16(qf, kf[ni], zero, 0, 0, 0);
    #pragma unroll
    for (int ni = 0; ni < 8; ++ni)
      #pragma unroll
      for (int i = 0; i < 4; ++i)
        S[ni][i] += mbase[(mi * 16 + quad * 4 + i) * 128 + ni * 16 + r16];
    float linv[4], mrow[4];
    #pragma unroll
    for (int i = 0; i < 4; ++i) {
      float m = S[0][i];
      #pragma unroll
      for (int ni = 1; ni < 8; ++ni) m = fmaxf(m, S[ni][i]);
      m = fmaxf(m, __shfl_xor(m, 1));
      m = fmaxf(m, __shfl_xor(m, 2));
      m = fmaxf(m, __shfl_xor(m, 4));
      m = fmaxf(m, __shfl_xor(m, 8));
      mrow[i] = m;
    }
    #pragma unroll
    for (int i = 0; i < 4; ++i) {
      float lsum = 0.f;
      #pragma unroll
      for (int ni = 0; ni < 8; ++ni) {
        const float pv = __expf(S[ni][i] - mrow[i]);
        S[ni][i] = pv;
        lsum += pv;
      }
      lsum += __shfl_xor(lsum, 1);
      lsum += __shfl_xor(lsum, 2);
      lsum += __shfl_xor(lsum, 4);
      lsum += __shfl_xor(lsum, 8);
      linv[i] = 1.f / lsum;
    }
    #pragma unroll
    for (int ni = 0; ni < 8; ++ni)
      #pragma unroll
      for (int i = 0; i < 4; ++i)
        P[(quad * 4 + i) * 136 + ni * 16 + r16] = f2bs(S[ni][i] * linv[i]);
    floatx4 O[2] = {zero, zero};
    #pragma unroll
    for (int s = 0; s < 4; ++s) {
      bf16x8 pf = *reinterpret_cast<const bf16x8*>(
          &P[r16 * 136 + s * 32 + quad * 8]);
      #pragma unroll
      for (int nj = 0; nj < 2; ++nj)
        O[nj] = __builtin_amdgcn_mfma_f32_16x16x32_bf16(pf, vf[s][nj], O[nj], 0, 0, 0);
    }
    #pragma unroll
    for (int nj = 0; nj < 2; ++nj)
      #pragma unroll
      for (int i = 0; i < 4; ++i) {
        const int addr = base + (mi * 16 + quad * 4 + i) * rstride + nj * 16 + r16;
        float val = O[nj][i];
        if (lepeadd) val += lepeadd[addr];
        vbuf[addr] = f2b(val);
      }
  }
}

// ---------------- K5: output projection via MFMA (bf16 pre -> fp32 out) -----
// v3: 2 row-fragments per wave (32 rows), full nt range per block (pre read
// once), operand-swapped MFMA -> single float4 store per rowset.
__global__ __launch_bounds__(256) void proj_mfma(
    const bf16* __restrict__ pre, const unsigned short* __restrict__ Wto,
    const float* __restrict__ bo, float* __restrict__ out) {
  const int wave = threadIdx.x >> 6, l = threadIdx.x & 63;
  const int r16 = l & 15, quad = l >> 4;
  const int row0 = blockIdx.x * 128 + wave * 32;
  const floatx4 zero = {0.f, 0.f, 0.f, 0.f};
  bf16x8 a[2][6];
  #pragma unroll
  for (int rs = 0; rs < 2; ++rs)
    #pragma unroll
    for (int kc = 0; kc < 6; ++kc)
      a[rs][kc] = *reinterpret_cast<const bf16x8*>(
          pre + (row0 + rs * 16 + r16) * CC + kc * 32 + quad * 8);
  #pragma unroll
  for (int nt = 0; nt < 12; ++nt) {
    bf16x8 wfr[6];
    #pragma unroll
    for (int kc = 0; kc < 6; ++kc)
      wfr[kc] = *reinterpret_cast<const bf16x8*>(
          Wto + (nt * 16 + r16) * CC + kc * 32 + quad * 8);
    floatx4 acc0 = zero, acc1 = zero;
    #pragma unroll
    for (int kc = 0; kc < 6; ++kc) {
      acc0 = __builtin_amdgcn_mfma_f32_16x16x32_bf16(wfr[kc], a[0][kc], acc0, 0, 0, 0);
      acc1 = __builtin_amdgcn_mfma_f32_16x16x32_bf16(wfr[kc], a[1][kc], acc1, 0, 0, 0);
    }
    const int col0 = nt * 16 + quad * 4;
    const float4 b4 = *reinterpret_cast<const float4*>(bo + col0);
    float4 s0 = make_float4(acc0[0] + b4.x, acc0[1] + b4.y,
                            acc0[2] + b4.z, acc0[3] + b4.w);
    float4 s1 = make_float4(acc1[0] + b4.x, acc1[1] + b4.y,
                            acc1[2] + b4.z, acc1[3] + b4.w);
    *reinterpret_cast<float4*>(&out[(row0 + r16) * CC + col0]) = s0;
    *reinterpret_cast<float4*>(&out[(row0 + 16 + r16) * CC + col0]) = s1;
  }
}

extern "C" void kernel_launch(void* const* d_in, const int* in_sizes, int n_in,
                              void* d_out, int out_size, void* d_ws, size_t ws_size,
                              hipStream_t stream) {
  const float* x      = (const float*)d_in[0];
  const float* mask_h = (const float*)d_in[1];
  const float* mask_w = (const float*)d_in[2];
  const float* Wq = (const float*)d_in[3];
  const float* bq = (const float*)d_in[4];
  const float* Wk = (const float*)d_in[5];
  const float* bk = (const float*)d_in[6];
  const float* Wv = (const float*)d_in[7];
  const float* bv = (const float*)d_in[8];
  const float* lw = (const float*)d_in[9];
  const float* lb = (const float*)d_in[10];
  const float* Wo = (const float*)d_in[11];
  const float* bo = (const float*)d_in[12];
  float* out = (float*)d_out;

  // ws: q bf16 | k bf16 | v bf16 (each NTOT) | Wt bf16 4x192x192 = 75.8 MB
  bf16* q    = (bf16*)d_ws;
  bf16* kbuf = q + NTOT;
  bf16* v    = kbuf + NTOT;
  unsigned short* Wt = (unsigned short*)(v + NTOT);

  prep_kernel<<<(4*CC*CC + 255)/256, 256, 0, stream>>>(Wq, Wk, Wv, Wo, Wt);
  qkv_mfma<<<(BB*HH*WW)/128, 256, 0, stream>>>(x, Wt, bq, bk, bv, q, kbuf, v);
  lepe_kernel<<<(NTOT/8 + 255)/256, 256, 0, stream>>>(v, lw, lb, out);  // out = lepe
  attn_mfma_kernel<<<BB*128*NHH, 64, 0, stream>>>(
      q, kbuf, v, mask_w, nullptr, CC, 0);                  // v := v1
  attn_mfma_kernel<<<BB*128*NHH, 64, 0, stream>>>(
      q, kbuf, v, mask_h, out, WW*CC, 1);                   // v := attn+lepe
  proj_mfma<<<(BB*HH*WW)/128, 256, 0, stream>>>(v, Wt + 3*CC*CC, bo, out);
}